// Round 3
// baseline (1426.147 us; speedup 1.0000x reference)
//
#include <hip/hip_runtime.h>
#include <math.h>

#define HN   64
#define FQN  32
#define INN  16
#define SNN  32
#define OSLN 32
#define LTN  63
#define NBN  1024
#define KXN  144

#define OUT_HR 8257536
#define OUT_HC 8323072

// ws layout (floats)
#define WS_HROW 0                      // [2][1024][64]
#define WS_HCOL 131072                 // [2][1024][64]
#define WS_RR   262144                 // [1024][64][32]
#define WS_RI   (WS_RR + 2097152)
#define WS_CR   (WS_RI + 2097152)
#define WS_CI   (WS_CR + 2097152)
#define WS_COS  (WS_CI + 2097152)      // [1024][32]
#define WS_SIN  (WS_COS + 32768)
#define WS_TOT  (WS_SIN + 32768)       // 8,716,288 floats (~33.3 MiB)

struct KParams {
  const float *x, *Wf, *Wq, *Bg, *Bq, *rcw, *rcb, *ccw, *ccb, *r_ow, *r_ob, *c_ow, *c_ob;
  float *ws;
  float *out;
};

__device__ __forceinline__ float bcast(float v, int k) {
  return __int_as_float(__builtin_amdgcn_readlane(__float_as_int(v), k));
}
__device__ __forceinline__ float sigmf(float x) { return 1.0f / (1.0f + expf(-x)); }

__global__ void init_kernel(float* ws) {
  size_t i0 = (size_t)blockIdx.x * blockDim.x + threadIdx.x;
  size_t stride = (size_t)gridDim.x * blockDim.x;
  for (size_t i = i0; i < (size_t)WS_COS; i += stride)
    ws[i] = (i < (size_t)WS_RR) ? 0.0f : 0.1f;
  for (size_t i = i0; i < 32768; i += stride) {
    int ct = (int)(i >> 5);
    int f  = (int)(i & 31);
    // mimic reference: omega = fp32(fp32(2*pi) * (f+1)) / 32, theta = ct * omega
    float om = (6.2831853071795862f * (float)(f + 1)) * 0.03125f;
    float th = (float)ct * om;
    ws[WS_COS + i] = cosf(th);
    ws[WS_SIN + i] = sinf(th);
  }
}

__global__ __launch_bounds__(256) void step_kernel(KParams p, int t) {
  __shared__ float gl[8][224];    // post-activation gates: [0,64)=ug [64,128)=og [128,192)=ig [192,224)=freq
  __shared__ float hold[8][64];   // own h (previous step)
  __shared__ float cvec[8][64];   // row_c / col_c

  const int blk = blockIdx.x;
  const bool isRow = (blk < 128);
  const int own0 = (isRow ? blk : blk - 128) << 3;   // first owned slot/id
  const int oc = own0 >> 5;                          // own chain index (r for row side, cc for col side)
  const int r  = isRow ? oc : ((oc + t) & 31);
  const int cc = isRow ? ((r - t) & 31) : oc;
  const int b0 = own0 & 31;
  const int tid = threadIdx.x;
  const int lane = tid & 63;

  const float* hrowR = p.ws + WS_HROW + (t & 1) * 65536;
  float*       hrowW = p.ws + WS_HROW + ((t + 1) & 1) * 65536;
  const float* hcolR = p.ws + WS_HCOL + (t & 1) * 65536;
  float*       hcolW = p.ws + WS_HCOL + ((t + 1) & 1) * 65536;

  // ---- load xcat fragments into per-wave registers ----
  float xc0[8], xc1[8], xc2[8];
  const int cdx = t - r;
  const bool av = (cdx >= 0) && (cdx < OSLN);
#pragma unroll
  for (int i = 0; i < 8; ++i) {
    int b = b0 + i;
    xc0[i] = hrowR[(((r << 5) | b) << 6) + lane];
    xc1[i] = hcolR[(((cc << 5) | b) << 6) + lane];
    xc2[i] = (av && lane < INN) ? p.x[(size_t)((((b << 5) | r) << 5) | cdx) * INN + lane] : 0.0f;
  }

  // ---- gates: 224 outputs per half-slot, K=144, 8 slots per thread ----
  const int j = (tid < 224) ? tid : 223;
  const float* Wrow;
  float bias;
  if (j < 192) {
    int jr = isRow ? ((j < 128) ? j : j + 128)
                   : ((j < 128) ? j + 128 : j + 192);
    Wrow = p.Wf + jr * KXN;
    bias = p.Bg[jr];
  } else {
    int jf = isRow ? (j - 192) : (j - 160);
    Wrow = p.Wq + jf * KXN;
    bias = p.Bq[jf];
  }

  float acc[8] = {0.f,0.f,0.f,0.f,0.f,0.f,0.f,0.f};

  for (int kb = 0; kb < 64; kb += 4) {
    float4 w4 = *(const float4*)(Wrow + kb);
    float wc[4] = {w4.x, w4.y, w4.z, w4.w};
#pragma unroll
    for (int c = 0; c < 4; ++c)
#pragma unroll
      for (int i = 0; i < 8; ++i)
        acc[i] = fmaf(wc[c], bcast(xc0[i], kb + c), acc[i]);
  }
  for (int kb = 64; kb < 128; kb += 4) {
    float4 w4 = *(const float4*)(Wrow + kb);
    float wc[4] = {w4.x, w4.y, w4.z, w4.w};
#pragma unroll
    for (int c = 0; c < 4; ++c)
#pragma unroll
      for (int i = 0; i < 8; ++i)
        acc[i] = fmaf(wc[c], bcast(xc1[i], kb - 64 + c), acc[i]);
  }
#pragma unroll
  for (int kb = 128; kb < 144; kb += 4) {
    float4 w4 = *(const float4*)(Wrow + kb);
    float wc[4] = {w4.x, w4.y, w4.z, w4.w};
#pragma unroll
    for (int c = 0; c < 4; ++c)
#pragma unroll
      for (int i = 0; i < 8; ++i)
        acc[i] = fmaf(wc[c], bcast(xc2[i], kb - 128 + c), acc[i]);
  }

  const float bm = (t < SNN && r <= t) ? 1.0f : 0.0f;
#pragma unroll
  for (int i = 0; i < 8; ++i) acc[i] = fmaf(bm, bias, acc[i]);

  if (tid < 224) {
    const bool isT = (tid >= 128 && tid < 192);
#pragma unroll
    for (int i = 0; i < 8; ++i)
      gl[i][tid] = isT ? tanhf(acc[i]) : sigmf(acc[i]);
  }
  if (tid < 64) {
#pragma unroll
    for (int i = 0; i < 8; ++i)
      hold[i][lane] = isRow ? xc0[i] : xc1[i];
  }
  __syncthreads();

  // ---- state update: thread = (h = tid>>2, f-block = (tid&3)*8) ----
  const int hh = tid >> 2;
  const int f0 = (tid & 3) << 3;
  float csv[8], snv[8], wfv[8];
  {
    int tcd = t - cc;
    int ctI = (tcd >= 0 && tcd < OSLN) ? ((cc << 5) + tcd) : 0;
    const float* cp = p.ws + WS_COS + (ctI << 5) + f0;
    const float* sp = p.ws + WS_SIN + (ctI << 5) + f0;
    *(float4*)(csv)     = *(const float4*)(cp);
    *(float4*)(csv + 4) = *(const float4*)(cp + 4);
    *(float4*)(snv)     = *(const float4*)(sp);
    *(float4*)(snv + 4) = *(const float4*)(sp + 4);
    const float* wsrc = isRow ? p.rcw : p.ccw;
#pragma unroll
    for (int fi = 0; fi < 8; ++fi) wfv[fi] = wsrc[f0 + fi];
  }
  const float cbv = isRow ? p.rcb[0] : p.ccb[0];
  float* Sr = p.ws + (isRow ? WS_RR : WS_CR);
  float* Si = p.ws + (isRow ? WS_RI : WS_CI);

#pragma unroll 2
  for (int i = 0; i < 8; ++i) {
    float ug = gl[i][hh];
    float og = gl[i][64 + hh];
    float ig = gl[i][128 + hh];
    float amp = og * ig;
    float fr[8];
    *(float4*)(fr)     = *(const float4*)(&gl[i][192 + f0]);
    *(float4*)(fr + 4) = *(const float4*)(&gl[i][192 + f0 + 4]);
    size_t base = ((size_t)(own0 + i) << 11) + ((size_t)tid << 3);
    float rrv[8], riv[8];
    *(float4*)(rrv)     = *(const float4*)(Sr + base);
    *(float4*)(rrv + 4) = *(const float4*)(Sr + base + 4);
    *(float4*)(riv)     = *(const float4*)(Si + base);
    *(float4*)(riv + 4) = *(const float4*)(Si + base + 4);
    float sq = 0.0f;
#pragma unroll
    for (int fi = 0; fi < 8; ++fi) {
      float ft = ug * fr[fi];
      rrv[fi] = fmaf(ft, rrv[fi], amp * csv[fi]);
      riv[fi] = fmaf(ft, riv[fi], amp * snv[fi]);
      sq = fmaf(fmaf(riv[fi], riv[fi], rrv[fi] * rrv[fi]), wfv[fi], sq);
    }
    *(float4*)(Sr + base)     = *(const float4*)(rrv);
    *(float4*)(Sr + base + 4) = *(const float4*)(rrv + 4);
    *(float4*)(Si + base)     = *(const float4*)(riv);
    *(float4*)(Si + base + 4) = *(const float4*)(riv + 4);
    sq += __shfl_xor(sq, 1);
    sq += __shfl_xor(sq, 2);
    if ((tid & 3) == 0) cvec[i][hh] = tanhf(sq + cbv);
  }
  __syncthreads();

  // ---- output matmul + h update: thread = (h' = tid&63, slots {mg, mg+4}) ----
  const int hp = tid & 63;
  const int mg = tid >> 6;
  const float* OW = (isRow ? p.r_ow : p.c_ow) + hp * HN;
  float u0 = 0.0f, u1 = 0.0f;
  for (int k = 0; k < 64; k += 4) {
    float4 w4 = *(const float4*)(OW + k);
    float wc[4] = {w4.x, w4.y, w4.z, w4.w};
#pragma unroll
    for (int c = 0; c < 4; ++c) {
      u0 = fmaf(wc[c], cvec[mg][k + c], u0);
      u1 = fmaf(wc[c], cvec[mg + 4][k + c], u1);
    }
  }
  const float ob = (isRow ? p.r_ob : p.c_ob)[hp];
#pragma unroll
  for (int s2 = 0; s2 < 2; ++s2) {
    int i = mg + (s2 << 2);
    float u = s2 ? u1 : u0;
    float ug = gl[i][hp];
    float ig = gl[i][128 + hp];
    float cval = cvec[i][hp];
    float pre = (1.0f - ug) * hold[i][hp] + ug * ig + u + ob;
    float hn = sigmf(pre) * cval;
    int b = b0 + i;
    int n = (r << 5) | b;
    if (isRow) {
      hrowW[(n << 6) + hp] = hn;
      p.out[(((size_t)n * LTN) + t) * 128 + hp] = hn;
      if (t >= 31 && r == t - 31)
        p.out[OUT_HR + (((b << 5) | r) << 6) + hp] = hn;
    } else {
      hcolW[(((cc << 5) | b) << 6) + hp] = hn;
      p.out[(((size_t)n * LTN) + t) * 128 + 64 + hp] = hn;
      if (t >= 31 && r == 31)
        p.out[OUT_HC + (((b << 5) | (t - 31)) << 6) + hp] = hn;
    }
  }
}

extern "C" void kernel_launch(void* const* d_in, const int* in_sizes, int n_in,
                              void* d_out, int out_size, void* d_ws, size_t ws_size,
                              hipStream_t stream) {
  KParams p;
  p.x    = (const float*)d_in[0];
  p.Wf   = (const float*)d_in[1];
  p.Wq   = (const float*)d_in[2];
  p.Bg   = (const float*)d_in[3];
  p.Bq   = (const float*)d_in[4];
  p.rcw  = (const float*)d_in[5];
  p.rcb  = (const float*)d_in[6];
  p.ccw  = (const float*)d_in[7];
  p.ccb  = (const float*)d_in[8];
  p.r_ow = (const float*)d_in[9];
  p.r_ob = (const float*)d_in[10];
  p.c_ow = (const float*)d_in[11];
  p.c_ob = (const float*)d_in[12];
  p.ws   = (float*)d_ws;
  p.out  = (float*)d_out;

  hipLaunchKernelGGL(init_kernel, dim3(512), dim3(256), 0, stream, p.ws);
  for (int t = 0; t < LTN; ++t)
    hipLaunchKernelGGL(step_kernel, dim3(256), dim3(256), 0, stream, p, t);
}

// Round 5
// 1335.463 us; speedup vs baseline: 1.0679x; 1.0679x over previous
//
#include <hip/hip_runtime.h>
#include <math.h>

#define HN   64
#define FQN  32
#define INN  16
#define SNN  32
#define OSLN 32
#define LTN  63
#define NBN  1024
#define KXN  144

#define OUT_HR 8257536
#define OUT_HC 8323072

// ws layout (floats)
#define WS_HROW 0                      // [2][1024][64]
#define WS_HCOL 131072                 // [2][1024][64]
#define WS_RR   262144                 // [1024][64][32]
#define WS_RI   (WS_RR + 2097152)
#define WS_CR   (WS_RI + 2097152)
#define WS_CI   (WS_CR + 2097152)
#define WS_COS  (WS_CI + 2097152)      // [1024][32]
#define WS_SIN  (WS_COS + 32768)
#define WS_TOT  (WS_SIN + 32768)       // 8,716,288 floats (~33.3 MiB)

struct KParams {
  const float *x, *Wf, *Wq, *Bg, *Bq, *rcw, *rcb, *ccw, *ccb, *r_ow, *r_ob, *c_ow, *c_ob;
  float *ws;
  float *out;
};

__device__ __forceinline__ float bcast(float v, int k) {
  return __int_as_float(__builtin_amdgcn_readlane(__float_as_int(v), k));
}
__device__ __forceinline__ float sigmf(float x) { return 1.0f / (1.0f + expf(-x)); }

__global__ void init_kernel(float* ws) {
  size_t i0 = (size_t)blockIdx.x * blockDim.x + threadIdx.x;
  size_t stride = (size_t)gridDim.x * blockDim.x;
  for (size_t i = i0; i < (size_t)WS_COS; i += stride)
    ws[i] = (i < (size_t)WS_RR) ? 0.0f : 0.1f;
  for (size_t i = i0; i < 32768; i += stride) {
    int ct = (int)(i >> 5);
    int f  = (int)(i & 31);
    float om = (6.2831853071795862f * (float)(f + 1)) * 0.03125f;
    float th = (float)ct * om;
    ws[WS_COS + i] = cosf(th);
    ws[WS_SIN + i] = sinf(th);
  }
}

// 512 blocks x 256 threads: 2 blocks/CU, 2 waves/SIMD. 4 half-slots per block.
__global__ __launch_bounds__(256) void step_kernel(KParams p, int t) {
  __shared__ float gl[4][224];    // post-activation gates per slot
  __shared__ float hold[4][64];   // own h (previous step)
  __shared__ float cvec[4][64];   // row_c / col_c

  const int blk = blockIdx.x;
  const bool isRow = (blk < 256);
  const int own0 = (isRow ? blk : blk - 256) << 2;   // first owned half-slot
  const int oc = own0 >> 5;                          // own chain index
  const int r  = isRow ? oc : ((oc + t) & 31);
  const int cc = isRow ? ((r - t) & 31) : oc;
  const int b0 = own0 & 31;
  const int tid = threadIdx.x;
  const int lane = tid & 63;

  const float* hrowR = p.ws + WS_HROW + (t & 1) * 65536;
  float*       hrowW = p.ws + WS_HROW + ((t + 1) & 1) * 65536;
  const float* hcolR = p.ws + WS_HCOL + (t & 1) * 65536;
  float*       hcolW = p.ws + WS_HCOL + ((t + 1) & 1) * 65536;

  // ---- load xcat fragments into per-wave registers ----
  float xc0[4], xc1[4], xc2[4];
  const int cdx = t - r;
  const bool av = (cdx >= 0) && (cdx < OSLN);
#pragma unroll
  for (int i = 0; i < 4; ++i) {
    int b = b0 + i;
    xc0[i] = hrowR[(((r << 5) | b) << 6) + lane];
    xc1[i] = hcolR[(((cc << 5) | b) << 6) + lane];
    xc2[i] = (av && lane < INN) ? p.x[(size_t)((((b << 5) | r) << 5) | cdx) * INN + lane] : 0.0f;
  }

  // ---- gates: 224 outputs per half-slot, K=144, 4 slots per thread ----
  const int j = (tid < 224) ? tid : 223;
  const float* Wrow;
  float bias;
  if (j < 192) {
    int jr = isRow ? ((j < 128) ? j : j + 128)
                   : ((j < 128) ? j + 128 : j + 192);
    Wrow = p.Wf + jr * KXN;
    bias = p.Bg[jr];
  } else {
    int jf = isRow ? (j - 192) : (j - 160);
    Wrow = p.Wq + jf * KXN;
    bias = p.Bq[jf];
  }

  float acc[4] = {0.f,0.f,0.f,0.f};

  for (int kb = 0; kb < 64; kb += 4) {
    float4 w4 = *(const float4*)(Wrow + kb);
    float wc[4] = {w4.x, w4.y, w4.z, w4.w};
#pragma unroll
    for (int c = 0; c < 4; ++c)
#pragma unroll
      for (int i = 0; i < 4; ++i)
        acc[i] = fmaf(wc[c], bcast(xc0[i], kb + c), acc[i]);
  }
  for (int kb = 64; kb < 128; kb += 4) {
    float4 w4 = *(const float4*)(Wrow + kb);
    float wc[4] = {w4.x, w4.y, w4.z, w4.w};
#pragma unroll
    for (int c = 0; c < 4; ++c)
#pragma unroll
      for (int i = 0; i < 4; ++i)
        acc[i] = fmaf(wc[c], bcast(xc1[i], kb - 64 + c), acc[i]);
  }
#pragma unroll
  for (int kb = 128; kb < 144; kb += 4) {
    float4 w4 = *(const float4*)(Wrow + kb);
    float wc[4] = {w4.x, w4.y, w4.z, w4.w};
#pragma unroll
    for (int c = 0; c < 4; ++c)
#pragma unroll
      for (int i = 0; i < 4; ++i)
        acc[i] = fmaf(wc[c], bcast(xc2[i], kb - 128 + c), acc[i]);
  }

  const float bm = (t < SNN && r <= t) ? 1.0f : 0.0f;
#pragma unroll
  for (int i = 0; i < 4; ++i) acc[i] = fmaf(bm, bias, acc[i]);

  if (tid < 224) {
    const bool isT = (tid >= 128 && tid < 192);
#pragma unroll
    for (int i = 0; i < 4; ++i)
      gl[i][tid] = isT ? tanhf(acc[i]) : sigmf(acc[i]);
  }
  if (tid < 64) {
#pragma unroll
    for (int i = 0; i < 4; ++i)
      hold[i][lane] = isRow ? xc0[i] : xc1[i];
  }
  __syncthreads();

  // ---- state update: thread = (h = tid>>2, f-block = (tid&3)*8) ----
  const int hh = tid >> 2;
  const int f0 = (tid & 3) << 3;
  float csv[8], snv[8], wfv[8];
  {
    int tcd = t - cc;
    int ctI = (tcd >= 0 && tcd < OSLN) ? ((cc << 5) + tcd) : 0;
    const float* cp = p.ws + WS_COS + (ctI << 5) + f0;
    const float* sp = p.ws + WS_SIN + (ctI << 5) + f0;
    *(float4*)(csv)     = *(const float4*)(cp);
    *(float4*)(csv + 4) = *(const float4*)(cp + 4);
    *(float4*)(snv)     = *(const float4*)(sp);
    *(float4*)(snv + 4) = *(const float4*)(sp + 4);
    const float* wsrc = isRow ? p.rcw : p.ccw;
#pragma unroll
    for (int fi = 0; fi < 8; ++fi) wfv[fi] = wsrc[f0 + fi];
  }
  const float cbv = isRow ? p.rcb[0] : p.ccb[0];
  float* Sr = p.ws + (isRow ? WS_RR : WS_CR);
  float* Si = p.ws + (isRow ? WS_RI : WS_CI);

#pragma unroll 2
  for (int i = 0; i < 4; ++i) {
    float ug = gl[i][hh];
    float og = gl[i][64 + hh];
    float ig = gl[i][128 + hh];
    float amp = og * ig;
    float fr[8];
    *(float4*)(fr)     = *(const float4*)(&gl[i][192 + f0]);
    *(float4*)(fr + 4) = *(const float4*)(&gl[i][192 + f0 + 4]);
    size_t base = ((size_t)(own0 + i) << 11) + ((size_t)tid << 3);
    float rrv[8], riv[8];
    *(float4*)(rrv)     = *(const float4*)(Sr + base);
    *(float4*)(rrv + 4) = *(const float4*)(Sr + base + 4);
    *(float4*)(riv)     = *(const float4*)(Si + base);
    *(float4*)(riv + 4) = *(const float4*)(Si + base + 4);
    float sq = 0.0f;
#pragma unroll
    for (int fi = 0; fi < 8; ++fi) {
      float ft = ug * fr[fi];
      rrv[fi] = fmaf(ft, rrv[fi], amp * csv[fi]);
      riv[fi] = fmaf(ft, riv[fi], amp * snv[fi]);
      sq = fmaf(fmaf(riv[fi], riv[fi], rrv[fi] * rrv[fi]), wfv[fi], sq);
    }
    *(float4*)(Sr + base)     = *(const float4*)(rrv);
    *(float4*)(Sr + base + 4) = *(const float4*)(rrv + 4);
    *(float4*)(Si + base)     = *(const float4*)(riv);
    *(float4*)(Si + base + 4) = *(const float4*)(riv + 4);
    sq += __shfl_xor(sq, 1);
    sq += __shfl_xor(sq, 2);
    if ((tid & 3) == 0) cvec[i][hh] = tanhf(sq + cbv);
  }
  __syncthreads();

  // ---- output matmul + h update: thread = (h' = tid&63, slot = tid>>6) ----
  const int hp = tid & 63;
  const int mg = tid >> 6;       // slot index 0..3
  const float* OW = (isRow ? p.r_ow : p.c_ow) + hp * HN;
  float u0 = 0.0f;
  for (int k = 0; k < 64; k += 4) {
    float4 w4 = *(const float4*)(OW + k);
    float wc[4] = {w4.x, w4.y, w4.z, w4.w};
#pragma unroll
    for (int c = 0; c < 4; ++c)
      u0 = fmaf(wc[c], cvec[mg][k + c], u0);
  }
  const float ob = (isRow ? p.r_ob : p.c_ob)[hp];
  {
    const int i = mg;
    float ug = gl[i][hp];
    float ig = gl[i][128 + hp];
    float cval = cvec[i][hp];
    float pre = (1.0f - ug) * hold[i][hp] + ug * ig + u0 + ob;
    float hn = sigmf(pre) * cval;
    int b = b0 + i;
    int n = (r << 5) | b;
    if (isRow) {
      hrowW[(n << 6) + hp] = hn;
      p.out[(((size_t)n * LTN) + t) * 128 + hp] = hn;
      if (t >= 31 && r == t - 31)
        p.out[OUT_HR + (((b << 5) | r) << 6) + hp] = hn;
    } else {
      hcolW[(((cc << 5) | b) << 6) + hp] = hn;
      p.out[(((size_t)n * LTN) + t) * 128 + 64 + hp] = hn;
      if (t >= 31 && r == 31)
        p.out[OUT_HC + (((b << 5) | (t - 31)) << 6) + hp] = hn;
    }
  }
}

extern "C" void kernel_launch(void* const* d_in, const int* in_sizes, int n_in,
                              void* d_out, int out_size, void* d_ws, size_t ws_size,
                              hipStream_t stream) {
  KParams p;
  p.x    = (const float*)d_in[0];
  p.Wf   = (const float*)d_in[1];
  p.Wq   = (const float*)d_in[2];
  p.Bg   = (const float*)d_in[3];
  p.Bq   = (const float*)d_in[4];
  p.rcw  = (const float*)d_in[5];
  p.rcb  = (const float*)d_in[6];
  p.ccw  = (const float*)d_in[7];
  p.ccb  = (const float*)d_in[8];
  p.r_ow = (const float*)d_in[9];
  p.r_ob = (const float*)d_in[10];
  p.c_ow = (const float*)d_in[11];
  p.c_ob = (const float*)d_in[12];
  p.ws   = (float*)d_ws;
  p.out  = (float*)d_out;

  hipLaunchKernelGGL(init_kernel, dim3(512), dim3(256), 0, stream, p.ws);
  for (int t = 0; t < LTN; ++t)
    hipLaunchKernelGGL(step_kernel, dim3(512), dim3(256), 0, stream, p, t);
}